// Round 3
// baseline (1554.367 us; speedup 1.0000x reference)
//
#include <hip/hip_runtime.h>

#define HD 256
#define KD 512

typedef _Float16 half8 __attribute__((ext_vector_type(8)));
typedef _Float16 half2v __attribute__((ext_vector_type(2)));
typedef _Float16 half4v __attribute__((ext_vector_type(4)));
typedef float floatx4 __attribute__((ext_vector_type(4)));
typedef float floatx2 __attribute__((ext_vector_type(2)));

__device__ __forceinline__ float sigmf_(float x) { return 1.f / (1.f + __expf(-x)); }
__device__ __forceinline__ float tanhf_(float x) {
  x = fminf(fmaxf(x, -15.f), 15.f);
  float e = __expf(2.f * x);
  return (e - 1.f) / (e + 1.f);
}

// ---------------------------------------------------------------------------
// prep: gate bias sums, leaf csum (=2*c_leaf), and leaf-level folded bias
// bias2[g][n] = bsum[g][n] + sum_k Wg[n][k] * 2*h_leaf[k]  (k < 256, h part)
// ---------------------------------------------------------------------------
__global__ void prep_kernel(const float* __restrict__ bf_, const float* __restrict__ b_f,
                            const float* __restrict__ bi_, const float* __restrict__ b_i,
                            const float* __restrict__ bu_, const float* __restrict__ b_u,
                            const float* __restrict__ bo_, const float* __restrict__ b_o,
                            const float* __restrict__ Wf, const float* __restrict__ Wi,
                            const float* __restrict__ Wu, const float* __restrict__ Wo,
                            float* __restrict__ bsum, float* __restrict__ bias2,
                            float* __restrict__ cleaf2)
{
  __shared__ float hl2[HD];
  int n = threadIdx.x;
  float sf = bf_[n] + b_f[n];
  float si = bi_[n] + b_i[n];
  float su = bu_[n] + b_u[n];
  float so = bo_[n] + b_o[n];
  bsum[n] = sf; bsum[HD + n] = si; bsum[2 * HD + n] = su; bsum[3 * HD + n] = so;
  float ig = 1.f / (1.f + expf(-si));
  float uu = tanhf(su);
  float cl = ig * uu;
  cleaf2[n] = cl + cl;
  float hl = (1.f / (1.f + expf(-so))) * tanhf(cl);
  hl2[n] = 2.f * hl;
  __syncthreads();
  const float* Ws[4] = {Wf, Wi, Wu, Wo};
  for (int g = 0; g < 4; ++g) {
    const float* w = Ws[g] + n * KD;
    float s = 0.f;
    for (int k = 0; k < HD; k += 4) {
      floatx4 wv = *(const floatx4*)(w + k);
      floatx4 hv = *(const floatx4*)(&hl2[k]);
      s += wv[0] * hv[0] + wv[1] * hv[1] + wv[2] * hv[2] + wv[3] * hv[3];
    }
    bias2[g * HD + n] = bsum[g * HD + n] + s;
  }
}

// ---------------------------------------------------------------------------
// convert the 4 gate weights (fp32, [256][512]) to f16 packed [g][256][512]
// ---------------------------------------------------------------------------
__global__ void wcvt_kernel(const float* __restrict__ Wf, const float* __restrict__ Wi,
                            const float* __restrict__ Wu, const float* __restrict__ Wo,
                            _Float16* __restrict__ Wh)
{
  int idx = (blockIdx.x * 256 + threadIdx.x) * 4;
  int g = idx >> 17;
  int rem = idx & ((1 << 17) - 1);
  const float* src = (g == 0) ? Wf : (g == 1) ? Wi : (g == 2) ? Wu : Wo;
  floatx4 v = *(const floatx4*)(src + rem);
  half4v o;
  o[0] = (_Float16)v[0]; o[1] = (_Float16)v[1]; o[2] = (_Float16)v[2]; o[3] = (_Float16)v[3];
  *(half4v*)(Wh + idx) = o;
}

// ---------------------------------------------------------------------------
// fused level kernel.
// block = 256 threads = 4 waves; wave = gate. Block tile: 64 rows x 64 cols
// per gate; grid = (M/64, 4), n0 = blockIdx.y*64.
// Inputs PRE-PAIR-SUMMED: hsum_in[m] = h[2m]+h[2m+1] (f16),
// csum_in[m] = c[2m]+c[2m+1] (f32). Outputs likewise for the parent level.
// leaf: skip h chunk (folded into bias2), csum_in = cleaf2 broadcast.
// fin : write per-root h to hsum_out (hr) instead of pair sums.
// __launch_bounds__(256,3): VGPR cap 170 -> room for B-prefetch regs,
// 3 blocks/CU = 12 waves/CU residency.
// ---------------------------------------------------------------------------
__global__ __launch_bounds__(256, 3)
void level_kernel(const _Float16* __restrict__ hsum_in,
                  const float* __restrict__ csum_in,
                  const float* __restrict__ embed,
                  const _Float16* __restrict__ Wh,
                  const float* __restrict__ bias,
                  _Float16* __restrict__ hsum_out,
                  float* __restrict__ csum_out,
                  int l, int leaf, int fin)
{
  __shared__ __attribute__((aligned(16))) char smraw[64 * 256 * 2];
  auto As = (_Float16(*)[256])smraw;     // 64 rows x 256 f16, XOR-swizzled groups
  auto Zs = (float(*)[16][66])smraw;     // [4 gates][16 rows][66 cols] (padded), aliased

  const int cnt = 1 << l;
  const int cs = (2 << l) - 1;
  const int m0 = blockIdx.x * 64;
  const int n0 = blockIdx.y * 64;
  const int t = threadIdx.x;
  const int g = t >> 6;                  // wave id = gate
  const int lane = t & 63;
  const int lm = lane & 15;
  const int quad = lane >> 4;

  floatx4 acc[4][4] = {};

  // staging mapping: row sr = t>>2 (0..63), quarter s4 = t&3 (64 consecutive k)
  const int sr = t >> 2;
  const int s4 = t & 3;
  const int sm = m0 + sr;
  const int sb = sm >> l;
  const int sj = sm & (cnt - 1);
  const long ebase = ((long)sb * 1023 + cs + 2 * sj) * 256;

  const _Float16* wg = Wh + (long)(g * HD + n0) * KD;

  // K-loop with explicit B double-buffer: ks+1's weight loads issue before
  // ks's MFMAs retire -> L2 latency hidden under matrix math.
  auto gemm_chunk = [&](int kbase) {
    const _Float16* wb = wg + kbase + quad * 8;
    half8 bcur[4], bnxt[4];
#pragma unroll
    for (int nt = 0; nt < 4; ++nt)
      bcur[nt] = *(const half8*)(wb + (long)(nt * 16 + lm) * KD);
#pragma unroll
    for (int ks = 0; ks < 8; ++ks) {
      if (ks < 7) {
#pragma unroll
        for (int nt = 0; nt < 4; ++nt)
          bnxt[nt] = *(const half8*)(wb + (long)(nt * 16 + lm) * KD + (ks + 1) * 32);
      }
      half8 afr[4];
#pragma unroll
      for (int mt = 0; mt < 4; ++mt) {
        int row = mt * 16 + lm;
        afr[mt] = *(const half8*)(&As[row][((ks * 4 + quad) ^ (row & 7)) * 8]);
      }
#pragma unroll
      for (int mt = 0; mt < 4; ++mt)
#pragma unroll
        for (int nt = 0; nt < 4; ++nt)
          acc[mt][nt] = __builtin_amdgcn_mfma_f32_16x16x32_f16(afr[mt], bcur[nt], acc[mt][nt], 0, 0, 0);
#pragma unroll
      for (int nt = 0; nt < 4; ++nt) bcur[nt] = bnxt[nt];
    }
  };

  if (!leaf) {
    // chunk 0: pre-summed child h (k 0..255) — pure f16 copy (temporal: L2-hot)
    const _Float16* hp = hsum_in + (long)sm * HD;
#pragma unroll
    for (int gi = 0; gi < 8; ++gi) {
      int gl = s4 * 8 + gi;
      half8 v = *(const half8*)(hp + gl * 8);
      *(half8*)(&As[sr][((gl ^ (sr & 7)) * 8)]) = v;
    }
    __syncthreads();
    gemm_chunk(0);
    __syncthreads();
  }

  // chunk 1: embed pair-sum (k 256..511 of W) — nt: streamed once per level
  {
    const float* e0 = embed + ebase;
    const float* e1 = e0 + 256;
#pragma unroll
    for (int gi = 0; gi < 8; ++gi) {
      int gl = s4 * 8 + gi;
      floatx4 x0 = __builtin_nontemporal_load((const floatx4*)(e0 + gl * 8));
      floatx4 x1 = __builtin_nontemporal_load((const floatx4*)(e0 + gl * 8 + 4));
      floatx4 y0 = __builtin_nontemporal_load((const floatx4*)(e1 + gl * 8));
      floatx4 y1 = __builtin_nontemporal_load((const floatx4*)(e1 + gl * 8 + 4));
      half8 s;
#pragma unroll
      for (int e = 0; e < 4; ++e) { s[e] = (_Float16)(x0[e] + y0[e]); s[4 + e] = (_Float16)(x1[e] + y1[e]); }
      *(half8*)(&As[sr][((gl ^ (sr & 7)) * 8)]) = s;
    }
  }
  __syncthreads();
  gemm_chunk(256);

  // ---------------- epilogue: 4 passes of 16 rows ----------------
  const int r0 = ((t >> 5) & 7) * 2;   // even row in [0,16)
  const int c2 = (t & 31) * 2;         // even col in [0,64)
  const int coln = n0 + c2;
  floatx2 bb[4];
#pragma unroll
  for (int g2 = 0; g2 < 4; ++g2) bb[g2] = *(const floatx2*)(bias + g2 * HD + coln);
  floatx2 clv = {0.f, 0.f};
  if (leaf) clv = *(const floatx2*)(csum_in + coln);

#pragma unroll 1
  for (int pass = 0; pass < 4; ++pass) {
    __syncthreads();
#pragma unroll
    for (int nt = 0; nt < 4; ++nt)
#pragma unroll
      for (int e = 0; e < 4; ++e)
        Zs[g][quad * 4 + e][nt * 16 + lm] = acc[pass][nt][e];
    __syncthreads();

    const int mmA = m0 + pass * 16 + r0;
    floatx2 csA, csB;
    if (leaf) { csA = clv; csB = clv; }
    else {
      csA = *(const floatx2*)(csum_in + (long)mmA * HD + coln);
      csB = *(const floatx2*)(csum_in + (long)(mmA + 1) * HD + coln);
    }
    float hs[2][2], cv[2][2];
#pragma unroll
    for (int rr = 0; rr < 2; ++rr)
#pragma unroll
      for (int cc = 0; cc < 2; ++cc) {
        float zf = Zs[0][r0 + rr][c2 + cc] + bb[0][cc];
        float zi = Zs[1][r0 + rr][c2 + cc] + bb[1][cc];
        float zu = Zs[2][r0 + rr][c2 + cc] + bb[2][cc];
        float zo = Zs[3][r0 + rr][c2 + cc] + bb[3][cc];
        float csv = rr ? csB[cc] : csA[cc];
        float f = sigmf_(zf), ig = sigmf_(zi), uu = tanhf_(zu), oo = sigmf_(zo);
        float cn = ig * uu + f * csv;
        cv[rr][cc] = cn;
        hs[rr][cc] = oo * tanhf_(cn);
      }
    if (fin) {
      half2v hv0; hv0[0] = (_Float16)hs[0][0]; hv0[1] = (_Float16)hs[0][1];
      half2v hv1; hv1[0] = (_Float16)hs[1][0]; hv1[1] = (_Float16)hs[1][1];
      *(half2v*)(hsum_out + (long)mmA * HD + coln) = hv0;
      *(half2v*)(hsum_out + (long)(mmA + 1) * HD + coln) = hv1;
    } else {
      const long pr = mmA >> 1;
      half2v hv; hv[0] = (_Float16)(hs[0][0] + hs[1][0]); hv[1] = (_Float16)(hs[0][1] + hs[1][1]);
      floatx2 cvv; cvv[0] = cv[0][0] + cv[1][0]; cvv[1] = cv[0][1] + cv[1][1];
      *(half2v*)(hsum_out + pr * HD + coln) = hv;
      *(floatx2*)(csum_out + pr * HD + coln) = cvv;
    }
  }
}

// ---------------------------------------------------------------------------
// fused head: y=tanh(hr@W1+b1); y2=relu(hr@W2+b2)@W3+b3; out=relu((y+y2)@W4+b4)
// one block per batch row, all stages through LDS
// ---------------------------------------------------------------------------
__global__ void head_all_kernel(const _Float16* __restrict__ hr,
                                const float* __restrict__ W1, const float* __restrict__ bl1,
                                const float* __restrict__ W2, const float* __restrict__ bl2,
                                const float* __restrict__ W3, const float* __restrict__ bl3,
                                const float* __restrict__ W4, const float* __restrict__ bl4,
                                float* __restrict__ out)
{
  __shared__ float a[HD];
  __shared__ float t1s[HD];
  __shared__ float t2s[HD];
  int b = blockIdx.x, n = threadIdx.x;
  a[n] = (float)hr[b * HD + n];
  __syncthreads();
  {
    const float* w1 = W1 + n * HD;
    const float* w2 = W2 + n * HD;
    float s1 = bl1[n], s2 = bl2[n];
    for (int k = 0; k < HD; k += 4) {
      floatx4 av = *(const floatx4*)(&a[k]);
      floatx4 w1v = *(const floatx4*)(w1 + k);
      floatx4 w2v = *(const floatx4*)(w2 + k);
#pragma unroll
      for (int e = 0; e < 4; ++e) { s1 += av[e] * w1v[e]; s2 += av[e] * w2v[e]; }
    }
    t1s[n] = tanhf_(s1);
    t2s[n] = fmaxf(s2, 0.f);
  }
  __syncthreads();
  {
    const float* w3 = W3 + n * HD;
    float s3 = bl3[n];
    for (int k = 0; k < HD; k += 4) {
      floatx4 av = *(const floatx4*)(&t2s[k]);
      floatx4 wv = *(const floatx4*)(w3 + k);
#pragma unroll
      for (int e = 0; e < 4; ++e) s3 += av[e] * wv[e];
    }
    __syncthreads();            // all stage-1 reads of a[] complete
    a[n] = t1s[n] + s3;
  }
  __syncthreads();
  {
    const float* w4 = W4 + n * HD;
    float s4 = bl4[n];
    for (int k = 0; k < HD; k += 4) {
      floatx4 av = *(const floatx4*)(&a[k]);
      floatx4 wv = *(const floatx4*)(w4 + k);
#pragma unroll
      for (int e = 0; e < 4; ++e) s4 += av[e] * wv[e];
    }
    out[b * HD + n] = fmaxf(s4, 0.f);
  }
}

// ---------------------------------------------------------------------------
extern "C" void kernel_launch(void* const* d_in, const int* in_sizes, int n_in,
                              void* d_out, int out_size, void* d_ws, size_t ws_size,
                              hipStream_t stream)
{
  (void)in_sizes; (void)n_in; (void)out_size; (void)ws_size;
  const float* embed = (const float*)d_in[0];
  const float* Wf  = (const float*)d_in[1];
  const float* bf_ = (const float*)d_in[2];
  const float* b_f = (const float*)d_in[3];
  const float* Wi  = (const float*)d_in[4];
  const float* bi_ = (const float*)d_in[5];
  const float* b_i = (const float*)d_in[6];
  const float* Wu  = (const float*)d_in[7];
  const float* bu_ = (const float*)d_in[8];
  const float* b_u = (const float*)d_in[9];
  const float* Wo  = (const float*)d_in[10];
  const float* bo_ = (const float*)d_in[11];
  const float* b_o = (const float*)d_in[12];
  const float* W1  = (const float*)d_in[13];
  const float* bl1 = (const float*)d_in[14];
  const float* W2  = (const float*)d_in[15];
  const float* bl2 = (const float*)d_in[16];
  const float* W3  = (const float*)d_in[17];
  const float* bl3 = (const float*)d_in[18];
  const float* W4  = (const float*)d_in[19];
  const float* bl4 = (const float*)d_in[20];

  char* ws = (char*)d_ws;
  _Float16* Wh   = (_Float16*)(ws);                 // 1,048,576 B
  float* bsum    = (float*)(ws + 1048576);          // 4 KB
  float* bias2   = (float*)(ws + 1052672);          // 4 KB
  float* cleaf2  = (float*)(ws + 1056768);          // 1 KB
  _Float16* hr   = (_Float16*)(ws + 1057792);       // 64 KB  (root h, f16)
  _Float16* HsA  = (_Float16*)(ws + 1516544);       // 8,388,608 B  (max: 16384x256 f16)
  float* CsA     = (float*)(ws + 9905152);          // 16,777,216 B (max: 16384x256 f32)
  _Float16* HsB  = (_Float16*)(ws + 26682368);      // 8,388,608 B
  float* CsB     = (float*)(ws + 35070976);         // 16,777,216 B -> end 51,848,192 B

  prep_kernel<<<dim3(1), dim3(256), 0, stream>>>(bf_, b_f, bi_, b_i, bu_, b_u, bo_, b_o,
                                                 Wf, Wi, Wu, Wo, bsum, bias2, cleaf2);
  wcvt_kernel<<<dim3(512), dim3(256), 0, stream>>>(Wf, Wi, Wu, Wo, Wh);

  _Float16* hbufs[2] = {HsA, HsB};
  float* cbufs[2] = {CsA, CsB};
  int pp = 0;
  const _Float16* hin = nullptr;
  const float* cin = cleaf2;
  for (int l = 8; l >= 0; --l) {
    const int leaf = (l == 8);
    const int fin = (l == 0);
    _Float16* hout = fin ? hr : hbufs[pp];
    float* cout = cbufs[pp];
    dim3 grid(2 << l, 4);
    level_kernel<<<grid, dim3(256), 0, stream>>>(hin, cin, embed, Wh,
                                                 leaf ? bias2 : bsum,
                                                 hout, cout, l, leaf, fin);
    hin = hbufs[pp];
    cin = cbufs[pp];
    pp ^= 1;
  }

  head_all_kernel<<<dim3(128), dim3(256), 0, stream>>>(hr, W1, bl1, W2, bl2, W3, bl3,
                                                       W4, bl4, (float*)d_out);
}

// Round 4
// 664.404 us; speedup vs baseline: 2.3395x; 2.3395x over previous
//
#include <hip/hip_runtime.h>

#define HD 256
#define KD 512

typedef _Float16 half8 __attribute__((ext_vector_type(8)));
typedef _Float16 half2v __attribute__((ext_vector_type(2)));
typedef _Float16 half4v __attribute__((ext_vector_type(4)));
typedef float floatx4 __attribute__((ext_vector_type(4)));
typedef float floatx2 __attribute__((ext_vector_type(2)));

__device__ __forceinline__ float sigmf_(float x) { return 1.f / (1.f + __expf(-x)); }
__device__ __forceinline__ float tanhf_(float x) {
  x = fminf(fmaxf(x, -15.f), 15.f);
  float e = __expf(2.f * x);
  return (e - 1.f) / (e + 1.f);
}

// ---------------------------------------------------------------------------
// prep: gate bias sums, leaf csum (=2*c_leaf), and leaf-level folded bias
// bias2[g][n] = bsum[g][n] + sum_k Wg[n][k] * 2*h_leaf[k]  (k < 256, h part)
// ---------------------------------------------------------------------------
__global__ void prep_kernel(const float* __restrict__ bf_, const float* __restrict__ b_f,
                            const float* __restrict__ bi_, const float* __restrict__ b_i,
                            const float* __restrict__ bu_, const float* __restrict__ b_u,
                            const float* __restrict__ bo_, const float* __restrict__ b_o,
                            const float* __restrict__ Wf, const float* __restrict__ Wi,
                            const float* __restrict__ Wu, const float* __restrict__ Wo,
                            float* __restrict__ bsum, float* __restrict__ bias2,
                            float* __restrict__ cleaf2)
{
  __shared__ float hl2[HD];
  int n = threadIdx.x;
  float sf = bf_[n] + b_f[n];
  float si = bi_[n] + b_i[n];
  float su = bu_[n] + b_u[n];
  float so = bo_[n] + b_o[n];
  bsum[n] = sf; bsum[HD + n] = si; bsum[2 * HD + n] = su; bsum[3 * HD + n] = so;
  float ig = 1.f / (1.f + expf(-si));
  float uu = tanhf(su);
  float cl = ig * uu;
  cleaf2[n] = cl + cl;
  float hl = (1.f / (1.f + expf(-so))) * tanhf(cl);
  hl2[n] = 2.f * hl;
  __syncthreads();
  const float* Ws[4] = {Wf, Wi, Wu, Wo};
  for (int g = 0; g < 4; ++g) {
    const float* w = Ws[g] + n * KD;
    float s = 0.f;
    for (int k = 0; k < HD; k += 4) {
      floatx4 wv = *(const floatx4*)(w + k);
      floatx4 hv = *(const floatx4*)(&hl2[k]);
      s += wv[0] * hv[0] + wv[1] * hv[1] + wv[2] * hv[2] + wv[3] * hv[3];
    }
    bias2[g * HD + n] = bsum[g * HD + n] + s;
  }
}

// ---------------------------------------------------------------------------
// convert the 4 gate weights (fp32, [256][512]) to f16 packed [g][256][512]
// ---------------------------------------------------------------------------
__global__ void wcvt_kernel(const float* __restrict__ Wf, const float* __restrict__ Wi,
                            const float* __restrict__ Wu, const float* __restrict__ Wo,
                            _Float16* __restrict__ Wh)
{
  int idx = (blockIdx.x * 256 + threadIdx.x) * 4;
  int g = idx >> 17;
  int rem = idx & ((1 << 17) - 1);
  const float* src = (g == 0) ? Wf : (g == 1) ? Wi : (g == 2) ? Wu : Wo;
  floatx4 v = *(const floatx4*)(src + rem);
  half4v o;
  o[0] = (_Float16)v[0]; o[1] = (_Float16)v[1]; o[2] = (_Float16)v[2]; o[3] = (_Float16)v[3];
  *(half4v*)(Wh + idx) = o;
}

// ---------------------------------------------------------------------------
// fused level kernel.
// block = 512 threads = 8 waves = (gate g = wave>>1) x (col-tile ct = wave&1)
// grid = (M/64, 2); n0 = blockIdx.y*128; block covers 64 rows x 128 cols.
// Inputs PRE-PAIR-SUMMED: hsum_in[m] = h[2m]+h[2m+1] (f16),
// csum_in[m] = c[2m]+c[2m+1] (f32). Outputs likewise for the parent level.
// leaf: skip h chunk (folded into bias2), csum_in = cleaf2 broadcast.
// fin : write per-root h to hsum_out (hr) instead of pair sums.
// NOTE: acc[][] must ONLY be indexed with compile-time constants — a runtime
// index sends the whole array to scratch (HBM) and MFMA throughput dies
// (rounds 1-3: MfmaUtil 2%, WRITE_SIZE ~1 GB of scratch traffic).
// ---------------------------------------------------------------------------
__global__ __launch_bounds__(512)
void level_kernel(const _Float16* __restrict__ hsum_in,
                  const float* __restrict__ csum_in,
                  const float* __restrict__ embed,
                  const _Float16* __restrict__ Wh,
                  const float* __restrict__ bias,
                  _Float16* __restrict__ hsum_out,
                  float* __restrict__ csum_out,
                  int l, int leaf, int fin)
{
  __shared__ __attribute__((aligned(16))) char smraw[4 * 16 * 132 * 4];
  auto As = (_Float16(*)[256])smraw;     // 64 rows x 256 f16, XOR-swizzled groups
  auto Zs = (float(*)[16][132])smraw;    // [4 gates][16 rows][132 cols] padded, aliased

  const int cnt = 1 << l;
  const int cs = (2 << l) - 1;
  const int m0 = blockIdx.x * 64;
  const int n0 = blockIdx.y * 128;
  const int t = threadIdx.x;
  const int wave = t >> 6;
  const int lane = t & 63;
  const int lm = lane & 15;
  const int quad = lane >> 4;
  const int g = wave >> 1;               // gate
  const int ct = wave & 1;               // column half

  floatx4 acc[4][4] = {};

  // staging mapping: row sr = t>>3 (0..63), granule lane c8 = t&7
  const int sr = t >> 3;
  const int c8 = t & 7;
  const int sm = m0 + sr;
  const int sb = sm >> l;
  const int sj = sm & (cnt - 1);
  const long ebase = ((long)sb * 1023 + cs + 2 * sj) * 256;

  const _Float16* wg = Wh + (long)(g * HD + n0 + ct * 64) * KD;

  // K-loop with explicit B double-buffer: ks+1's weight loads issue before
  // ks's MFMAs -> L2 latency hidden under matrix math. All indices static.
  auto gemm_chunk = [&](int kbase) {
    const _Float16* wb = wg + kbase + quad * 8;
    half8 bcur[4], bnxt[4];
#pragma unroll
    for (int nt = 0; nt < 4; ++nt)
      bcur[nt] = *(const half8*)(wb + (long)(nt * 16 + lm) * KD);
#pragma unroll
    for (int ks = 0; ks < 8; ++ks) {
      if (ks < 7) {
#pragma unroll
        for (int nt = 0; nt < 4; ++nt)
          bnxt[nt] = *(const half8*)(wb + (long)(nt * 16 + lm) * KD + (ks + 1) * 32);
      }
      half8 afr[4];
#pragma unroll
      for (int mt = 0; mt < 4; ++mt) {
        int row = mt * 16 + lm;
        afr[mt] = *(const half8*)(&As[row][((ks * 4 + quad) ^ (row & 7)) * 8]);
      }
#pragma unroll
      for (int mt = 0; mt < 4; ++mt)
#pragma unroll
        for (int nt = 0; nt < 4; ++nt)
          acc[mt][nt] = __builtin_amdgcn_mfma_f32_16x16x32_f16(afr[mt], bcur[nt], acc[mt][nt], 0, 0, 0);
#pragma unroll
      for (int nt = 0; nt < 4; ++nt) bcur[nt] = bnxt[nt];
    }
  };

  if (!leaf) {
    // chunk 0: pre-summed child h (k 0..255) — pure f16 copy (temporal: L2-hot)
    const _Float16* hp = hsum_in + (long)sm * HD;
#pragma unroll
    for (int gi = 0; gi < 4; ++gi) {
      int gl = gi * 8 + c8;
      half8 v = *(const half8*)(hp + gl * 8);
      *(half8*)(&As[sr][((gl ^ (sr & 7)) * 8)]) = v;
    }
    __syncthreads();
    gemm_chunk(0);
    __syncthreads();
  }

  // chunk 1: embed pair-sum (k 256..511 of W) — nt: streamed once per level
  {
    const float* e0 = embed + ebase;
    const float* e1 = e0 + 256;
#pragma unroll
    for (int gi = 0; gi < 4; ++gi) {
      int gl = gi * 8 + c8;
      floatx4 x0 = __builtin_nontemporal_load((const floatx4*)(e0 + gl * 8));
      floatx4 x1 = __builtin_nontemporal_load((const floatx4*)(e0 + gl * 8 + 4));
      floatx4 y0 = __builtin_nontemporal_load((const floatx4*)(e1 + gl * 8));
      floatx4 y1 = __builtin_nontemporal_load((const floatx4*)(e1 + gl * 8 + 4));
      half8 s;
#pragma unroll
      for (int e = 0; e < 4; ++e) { s[e] = (_Float16)(x0[e] + y0[e]); s[4 + e] = (_Float16)(x1[e] + y1[e]); }
      *(half8*)(&As[sr][((gl ^ (sr & 7)) * 8)]) = s;
    }
  }
  __syncthreads();
  gemm_chunk(256);

  // ---------------- epilogue: 4 fully-unrolled 16-row slabs ----------------
  // wave rp = t>>6 handles row-pair (2rp, 2rp+1) of the slab; lane covers 2 cols
  const int rp = t >> 6;                 // 0..7
  const int c2 = (t & 63) * 2;           // 0..126
  const int coln = n0 + c2;
  floatx2 bb[4];
#pragma unroll
  for (int g2 = 0; g2 < 4; ++g2) bb[g2] = *(const floatx2*)(bias + g2 * HD + coln);
  floatx2 clv = {0.f, 0.f};
  if (leaf) clv = *(const floatx2*)(csum_in + coln);

#pragma unroll
  for (int mt = 0; mt < 4; ++mt) {
    __syncthreads();
#pragma unroll
    for (int nt = 0; nt < 4; ++nt)
#pragma unroll
      for (int e = 0; e < 4; ++e)
        Zs[g][quad * 4 + e][ct * 64 + nt * 16 + lm] = acc[mt][nt][e];
    __syncthreads();

    const int mmA = m0 + mt * 16 + 2 * rp;
    floatx2 csA, csB;
    if (leaf) { csA = clv; csB = clv; }
    else {
      csA = *(const floatx2*)(csum_in + (long)mmA * HD + coln);
      csB = *(const floatx2*)(csum_in + (long)(mmA + 1) * HD + coln);
    }
    float hs[2][2], cv[2][2];
#pragma unroll
    for (int rr = 0; rr < 2; ++rr)
#pragma unroll
      for (int cc = 0; cc < 2; ++cc) {
        float zf = Zs[0][2 * rp + rr][c2 + cc] + bb[0][cc];
        float zi = Zs[1][2 * rp + rr][c2 + cc] + bb[1][cc];
        float zu = Zs[2][2 * rp + rr][c2 + cc] + bb[2][cc];
        float zo = Zs[3][2 * rp + rr][c2 + cc] + bb[3][cc];
        float csv = rr ? csB[cc] : csA[cc];
        float f = sigmf_(zf), ig = sigmf_(zi), uu = tanhf_(zu), oo = sigmf_(zo);
        float cn = ig * uu + f * csv;
        cv[rr][cc] = cn;
        hs[rr][cc] = oo * tanhf_(cn);
      }
    if (fin) {
      half2v hv0; hv0[0] = (_Float16)hs[0][0]; hv0[1] = (_Float16)hs[0][1];
      half2v hv1; hv1[0] = (_Float16)hs[1][0]; hv1[1] = (_Float16)hs[1][1];
      *(half2v*)(hsum_out + (long)mmA * HD + coln) = hv0;
      *(half2v*)(hsum_out + (long)(mmA + 1) * HD + coln) = hv1;
    } else {
      const long pr = mmA >> 1;
      half2v hv; hv[0] = (_Float16)(hs[0][0] + hs[1][0]); hv[1] = (_Float16)(hs[0][1] + hs[1][1]);
      floatx2 cvv; cvv[0] = cv[0][0] + cv[1][0]; cvv[1] = cv[0][1] + cv[1][1];
      *(half2v*)(hsum_out + pr * HD + coln) = hv;
      *(floatx2*)(csum_out + pr * HD + coln) = cvv;
    }
  }
}

// ---------------------------------------------------------------------------
// fused head: y=tanh(hr@W1+b1); y2=relu(hr@W2+b2)@W3+b3; out=relu((y+y2)@W4+b4)
// one block per batch row, all stages through LDS
// ---------------------------------------------------------------------------
__global__ void head_all_kernel(const _Float16* __restrict__ hr,
                                const float* __restrict__ W1, const float* __restrict__ bl1,
                                const float* __restrict__ W2, const float* __restrict__ bl2,
                                const float* __restrict__ W3, const float* __restrict__ bl3,
                                const float* __restrict__ W4, const float* __restrict__ bl4,
                                float* __restrict__ out)
{
  __shared__ float a[HD];
  __shared__ float t1s[HD];
  __shared__ float t2s[HD];
  int b = blockIdx.x, n = threadIdx.x;
  a[n] = (float)hr[b * HD + n];
  __syncthreads();
  {
    const float* w1 = W1 + n * HD;
    const float* w2 = W2 + n * HD;
    float s1 = bl1[n], s2 = bl2[n];
    for (int k = 0; k < HD; k += 4) {
      floatx4 av = *(const floatx4*)(&a[k]);
      floatx4 w1v = *(const floatx4*)(w1 + k);
      floatx4 w2v = *(const floatx4*)(w2 + k);
#pragma unroll
      for (int e = 0; e < 4; ++e) { s1 += av[e] * w1v[e]; s2 += av[e] * w2v[e]; }
    }
    t1s[n] = tanhf_(s1);
    t2s[n] = fmaxf(s2, 0.f);
  }
  __syncthreads();
  {
    const float* w3 = W3 + n * HD;
    float s3 = bl3[n];
    for (int k = 0; k < HD; k += 4) {
      floatx4 av = *(const floatx4*)(&t2s[k]);
      floatx4 wv = *(const floatx4*)(w3 + k);
#pragma unroll
      for (int e = 0; e < 4; ++e) s3 += av[e] * wv[e];
    }
    __syncthreads();            // all stage-1 reads of a[] complete
    a[n] = t1s[n] + s3;
  }
  __syncthreads();
  {
    const float* w4 = W4 + n * HD;
    float s4 = bl4[n];
    for (int k = 0; k < HD; k += 4) {
      floatx4 av = *(const floatx4*)(&a[k]);
      floatx4 wv = *(const floatx4*)(w4 + k);
#pragma unroll
      for (int e = 0; e < 4; ++e) s4 += av[e] * wv[e];
    }
    out[b * HD + n] = fmaxf(s4, 0.f);
  }
}

// ---------------------------------------------------------------------------
extern "C" void kernel_launch(void* const* d_in, const int* in_sizes, int n_in,
                              void* d_out, int out_size, void* d_ws, size_t ws_size,
                              hipStream_t stream)
{
  (void)in_sizes; (void)n_in; (void)out_size; (void)ws_size;
  const float* embed = (const float*)d_in[0];
  const float* Wf  = (const float*)d_in[1];
  const float* bf_ = (const float*)d_in[2];
  const float* b_f = (const float*)d_in[3];
  const float* Wi  = (const float*)d_in[4];
  const float* bi_ = (const float*)d_in[5];
  const float* b_i = (const float*)d_in[6];
  const float* Wu  = (const float*)d_in[7];
  const float* bu_ = (const float*)d_in[8];
  const float* b_u = (const float*)d_in[9];
  const float* Wo  = (const float*)d_in[10];
  const float* bo_ = (const float*)d_in[11];
  const float* b_o = (const float*)d_in[12];
  const float* W1  = (const float*)d_in[13];
  const float* bl1 = (const float*)d_in[14];
  const float* W2  = (const float*)d_in[15];
  const float* bl2 = (const float*)d_in[16];
  const float* W3  = (const float*)d_in[17];
  const float* bl3 = (const float*)d_in[18];
  const float* W4  = (const float*)d_in[19];
  const float* bl4 = (const float*)d_in[20];

  char* ws = (char*)d_ws;
  _Float16* Wh   = (_Float16*)(ws);                 // 1,048,576 B
  float* bsum    = (float*)(ws + 1048576);          // 4 KB
  float* bias2   = (float*)(ws + 1052672);          // 4 KB
  float* cleaf2  = (float*)(ws + 1056768);          // 1 KB
  _Float16* hr   = (_Float16*)(ws + 1057792);       // 64 KB  (root h, f16)
  _Float16* HsA  = (_Float16*)(ws + 1516544);       // 8,388,608 B  (max: 16384x256 f16)
  float* CsA     = (float*)(ws + 9905152);          // 16,777,216 B (max: 16384x256 f32)
  _Float16* HsB  = (_Float16*)(ws + 26682368);      // 8,388,608 B
  float* CsB     = (float*)(ws + 35070976);         // 16,777,216 B -> end 51,848,192 B

  prep_kernel<<<dim3(1), dim3(256), 0, stream>>>(bf_, b_f, bi_, b_i, bu_, b_u, bo_, b_o,
                                                 Wf, Wi, Wu, Wo, bsum, bias2, cleaf2);
  wcvt_kernel<<<dim3(512), dim3(256), 0, stream>>>(Wf, Wi, Wu, Wo, Wh);

  _Float16* hbufs[2] = {HsA, HsB};
  float* cbufs[2] = {CsA, CsB};
  int pp = 0;
  const _Float16* hin = nullptr;
  const float* cin = cleaf2;
  for (int l = 8; l >= 0; --l) {
    const int leaf = (l == 8);
    const int fin = (l == 0);
    _Float16* hout = fin ? hr : hbufs[pp];
    float* cout = cbufs[pp];
    dim3 grid(2 << l, 2);
    level_kernel<<<grid, dim3(512), 0, stream>>>(hin, cin, embed, Wh,
                                                 leaf ? bias2 : bsum,
                                                 hout, cout, l, leaf, fin);
    hin = hbufs[pp];
    cin = cbufs[pp];
    pp ^= 1;
  }

  head_all_kernel<<<dim3(128), dim3(256), 0, stream>>>(hr, W1, bl1, W2, bl2, W3, bl3,
                                                       W4, bl4, (float*)d_out);
}